// Round 7
// baseline (197.938 us; speedup 1.0000x reference)
//
#include <hip/hip_runtime.h>

#define B_    2
#define N_    2304
#define C_    768
#define HEADS 12
#define D_    64
#define F3    2304
#define M_    (B_*N_)        // 4608
#define SPLITS 2
#define KSPAN (N_/SPLITS)    // 1152
// SCALE(0.125) * log2(e) folded into Q at qkv epilogue:
#define QSCALE 0.18033688011112042f

typedef __attribute__((ext_vector_type(8)))  short bfrag;    // 8 x bf16 (4 VGPR)
typedef __attribute__((ext_vector_type(4)))  float ffrag;    // 16x16 acc
typedef __attribute__((ext_vector_type(16))) float ffrag16;  // 32x32 acc
typedef __attribute__((ext_vector_type(4)))  unsigned ufrag; // 4 x b32 = 8 bf16
typedef __attribute__((ext_vector_type(2)))  unsigned uint2v;

__device__ __forceinline__ short f2bf(float f) {
    unsigned u = __float_as_uint(f);
    u += 0x7fff + ((u >> 16) & 1);          // RNE
    return (short)(u >> 16);
}

__device__ __forceinline__ void gl2lds16(const void* g, void* l) {
    __builtin_amdgcn_global_load_lds(
        (const __attribute__((address_space(1))) void*)g,
        (__attribute__((address_space(3))) void*)l, 16, 0, 0);
}

// Counted waits (T4): never drain the just-issued prefetch. "memory"
// clobber keeps ds_read/global ops from crossing.
__device__ __forceinline__ void wait_vm4() { asm volatile("s_waitcnt vmcnt(4)" ::: "memory"); }
__device__ __forceinline__ void wait_vm0() { asm volatile("s_waitcnt vmcnt(0)" ::: "memory"); }

// trunc-pack two fp32 -> (bf16(a) low | bf16(b) high) in ONE v_perm_b32.
// bias-safe here because numerator (PV) and denominator (ones-MFMA) both
// consume the same truncated fragments -> common bias cancels in the ratio.
__device__ __forceinline__ unsigned pktrunc(float a, float b) {
    return __builtin_amdgcn_perm(__float_as_uint(a), __float_as_uint(b),
                                 0x03020706u);
}

// ---------------------------------------------------------------------------
// Fused fp32 -> bf16 cast of x, qkv_w, proj_w (dsts contiguous in ws).
// ---------------------------------------------------------------------------
__global__ __launch_bounds__(256) void cast_all(const float* __restrict__ x,
                                                const float* __restrict__ qw,
                                                const float* __restrict__ pw,
                                                short* __restrict__ dst) {
    const int nx4 = (M_*C_)/4, nq4 = (F3*C_)/4, np4 = (C_*C_)/4;
    int i = blockIdx.x * 256 + threadIdx.x;
    if (i >= nx4 + nq4 + np4) return;
    const float* src; int off;
    if (i < nx4)            { src = x;  off = i; }
    else if (i < nx4 + nq4) { src = qw; off = i - nx4; }
    else                    { src = pw; off = i - nx4 - nq4; }
    float4 v = ((const float4*)src)[off];
    short4 o;
    o.x = f2bf(v.x); o.y = f2bf(v.y); o.z = f2bf(v.z); o.w = f2bf(v.w);
    ((short4*)dst)[i] = o;
}

// ---------------------------------------------------------------------------
// QKV GEMM: qkv[m][f] = sum_c x[m][c]*w[f][c]  (NT), m97 structure
// + 3-deep LDS ring, SINGLE barrier per K-step:
//   {issue loads(t+1)->slot[(t+1)%3]; vmcnt(4); s_barrier; compute slot[t%3]}
//   WAR proof: slot[(t+1)%3] was last read at step t-2, whose ds_reads
//   retire before that wave's barrier(t-1); the prefetch issues only after
//   the issuing wave passed barrier(t-1) -> barrier(t-1) separates them.
//   Removing the trailing barrier lets waves drift a phase apart (MFMA of
//   one wave covers staging/VALU of another on the same SIMD).
// + XCD-chunked blockIdx swizzle (648 % 8 == 0 -> bijective).
// Q stored pre-scaled by SCALE*log2e; V stored transposed [bh,d,n].
// ---------------------------------------------------------------------------
__global__ __launch_bounds__(256) void qkv_gemm(const short* __restrict__ xb,
                                                const short* __restrict__ wb,
                                                short* __restrict__ Qb,
                                                short* __restrict__ Kb,
                                                short* __restrict__ Vtb) {
    __shared__ short As[3][128*32];
    __shared__ short Bs[3][128*32];
    const int t = threadIdx.x;
    const int w = t >> 6, lane = t & 63;
    const int quad = lane >> 4, l15 = lane & 15;
    const int wr = w >> 1, wc = w & 1;

    const int nwg = gridDim.x * gridDim.y;
    const int bid = blockIdx.y * gridDim.x + blockIdx.x;
    const int swz = (bid & 7) * (nwg >> 3) + (bid >> 3);
    const int m0 = (swz / gridDim.x) * 128, f0 = (swz % gridDim.x) * 128;

    const int srow = lane >> 2;            // row within 16-row segment
    const int skk  = (lane & 3) * 8;       // bf16 offset within 32-col row

    ffrag acc[4][4] = {};

    // prologue: issue K-step 0 into slot 0 (4 loads, not waited here)
    #pragma unroll
    for (int r = 0; r < 2; ++r) {
        int seg = r*4 + w;
        int row = seg*16 + srow;
        gl2lds16(xb + (size_t)(m0+row)*C_ + skk, As[0] + seg*512);
        gl2lds16(wb + (size_t)(f0+row)*C_ + skk, Bs[0] + seg*512);
    }

    const int NKT = C_/32;                 // 24
    int cur = 0;
    for (int kt = 0; kt < NKT; ++kt) {
        int nxt = cur + 1; if (nxt == 3) nxt = 0;
        if (kt + 1 < NKT) {                // prefetch next K-step into slot nxt
            const int k0n = (kt+1)*32;
            #pragma unroll
            for (int r = 0; r < 2; ++r) {
                int seg = r*4 + w;
                int row = seg*16 + srow;
                gl2lds16(xb + (size_t)(m0+row)*C_ + k0n + skk, As[nxt] + seg*512);
                gl2lds16(wb + (size_t)(f0+row)*C_ + k0n + skk, Bs[nxt] + seg*512);
            }
            wait_vm4();                    // tile kt landed; kt+1 in flight
        } else {
            wait_vm0();
        }
        __builtin_amdgcn_s_barrier();      // tile kt visible to all waves

        bfrag af[4], bf[4];
        #pragma unroll
        for (int i = 0; i < 4; ++i)
            af[i] = *(const bfrag*)(As[cur] + (wr*64 + i*16 + l15)*32 + quad*8);
        #pragma unroll
        for (int j = 0; j < 4; ++j)
            bf[j] = *(const bfrag*)(Bs[cur] + (wc*64 + j*16 + l15)*32 + quad*8);
        #pragma unroll
        for (int i = 0; i < 4; ++i)
            #pragma unroll
            for (int j = 0; j < 4; ++j)
                acc[i][j] = __builtin_amdgcn_mfma_f32_16x16x32_bf16(af[i], bf[j], acc[i][j], 0, 0, 0);
        cur = nxt;                         // no trailing barrier (3-ring WAR-safe)
    }

    const int b   = m0 / N_;
    const int seg = f0 + wc*64;
    const int which = seg / C_;                  // 0=Q 1=K 2=V
    const int head  = (seg - which*C_) >> 6;
    const int bh    = b*HEADS + head;
    const int nbase = (m0 - b*N_) + wr*64 + quad*4;

    if (which == 0) {
        #pragma unroll
        for (int i = 0; i < 4; ++i) {
            int n0 = nbase + i*16;
            #pragma unroll
            for (int j = 0; j < 4; ++j) {
                int d = j*16 + l15;
                #pragma unroll
                for (int r = 0; r < 4; ++r)
                    Qb[((size_t)bh*N_ + n0 + r)*D_ + d] = f2bf(acc[i][j][r] * QSCALE);
            }
        }
    } else if (which == 1) {
        #pragma unroll
        for (int i = 0; i < 4; ++i) {
            int n0 = nbase + i*16;
            #pragma unroll
            for (int j = 0; j < 4; ++j) {
                int d = j*16 + l15;
                #pragma unroll
                for (int r = 0; r < 4; ++r)
                    Kb[((size_t)bh*N_ + n0 + r)*D_ + d] = f2bf(acc[i][j][r]);
            }
        }
    } else {
        #pragma unroll
        for (int i = 0; i < 4; ++i) {
            int n0 = nbase + i*16;
            #pragma unroll
            for (int j = 0; j < 4; ++j) {
                int d = j*16 + l15;
                short4 vv;
                vv.x = f2bf(acc[i][j][0]);
                vv.y = f2bf(acc[i][j][1]);
                vv.z = f2bf(acc[i][j][2]);
                vv.w = f2bf(acc[i][j][3]);
                *(short4*)(Vtb + ((size_t)bh*D_ + d)*N_ + n0) = vv;
            }
        }
    }
}

// ---------------------------------------------------------------------------
// Flash attention, 32x32x16 bf16 MFMA, no-max softmax, split-K over grid.z.
// 3-deep K/V LDS ring (3 x 16 KiB slots), SINGLE barrier per tile (same WAR
// proof as qkv_gemm) -> waves can drift a phase apart, so one wave's MFMAs
// overlap another's exp2/pack VALU phase on the same SIMD. vmcnt(4) counted
// prefetch kept. Q tile overlays slot 1 during the prologue only (consumed
// into registers before slot 1 is first overwritten at tile 1's prefetch).
// l via ones-MFMA (r5 A/B: VALU l-sum put 60 ops on the critical path).
// Grid (N/128, B*H, SPLITS) + XCD-chunk swizzle.
// LDS rows 128B, XOR-swizzled: chunk c of row r lives at (c ^ (r&7))*16B.
// 32x32 C layout: col = lane&31, row = (reg&3) + 8*(reg>>2) + 4*(lane>>5).
// ---------------------------------------------------------------------------
__global__ __launch_bounds__(256, 4) void attn_mfma(const short* __restrict__ Qb,
                                                    const short* __restrict__ Kb,
                                                    const short* __restrict__ Vtb,
                                                    float* __restrict__ Opart,
                                                    float* __restrict__ lpart) {
    // 48 KiB total: slot s at lds + s*8192 shorts (K 4096 | V 4096).
    __shared__ short lds[24576];
    const int t = threadIdx.x;
    const int w = t >> 6, lane = t & 63;
    const int l31 = lane & 31, hi = lane >> 5;

    // XCD-chunk swizzle over the (qtile, bh) plane: fid is qtile-fastest.
    const int nwg = gridDim.x * gridDim.y;            // 432
    const int fid = blockIdx.y * gridDim.x + blockIdx.x;
    const int swz = (fid & 7) * (nwg >> 3) + (fid >> 3);
    const int bh  = swz / gridDim.x;
    const int q0  = (swz - bh * gridDim.x) * 128;

    const int split = blockIdx.z;
    const int kbase = split * KSPAN;
    const size_t base = (size_t)bh * N_ * D_;
    const int lrow = lane >> 3;            // row within 8-row segment
    const int lc   = (lane & 7) ^ lrow;    // swizzled source chunk

    short* Qs = lds + 8192;                // overlays slot 1

    // prologue: stage Q tile (128 x 64) into slot1 region, K/V tile 0 into slot0
    #pragma unroll
    for (int r = 0; r < 4; ++r) {
        int s = r*4 + w;
        gl2lds16(Qb + base + (size_t)(q0 + s*8 + lrow)*D_ + lc*8, Qs + s*512);
    }
    #pragma unroll
    for (int r = 0; r < 2; ++r) {
        int s = r*4 + w;
        int row = s*8 + lrow;
        gl2lds16(Kb  + base + (size_t)(kbase+row)*D_ + lc*8,    lds + s*512);
        gl2lds16(Vtb + (size_t)(bh*D_ + row)*N_ + kbase + lc*8, lds + 4096 + s*512);
    }
    __syncthreads();                       // Q + tile0 staged (full drain, once)

    // hoist Q B-frags (loop-invariant)
    bfrag qf[4];
    {
        int row = w*32 + l31, r7 = row & 7;
        #pragma unroll
        for (int kc = 0; kc < 4; ++kc)
            qf[kc] = *(const bfrag*)(Qs + row*64 + ((kc*2 + hi) ^ r7)*8);
    }
    __syncthreads();                       // Q-frag reads done before slot1 reuse

    // ones B-frag for the l (row-sum) MFMA
    bfrag vones;
    #pragma unroll
    for (int j = 0; j < 8; ++j) vones[j] = (short)0x3f80;

    ffrag16 oacc[2], lfr;
    #pragma unroll
    for (int r = 0; r < 16; ++r) { oacc[0][r] = 0.f; oacc[1][r] = 0.f; lfr[r] = 0.f; }

    const int NT = KSPAN / 64;             // 18
    int cur = 0;
    for (int ti = 0; ti < NT; ++ti) {
        int nxt = cur + 1; if (nxt == 3) nxt = 0;
        const short* Kc = lds + cur*8192;
        const short* Vc = Kc + 4096;

        // issue next tile's staging into slot nxt; counted wait — tile ti's
        // loads have had a full iteration to complete, prefetch stays in flight
        if (ti + 1 < NT) {
            short* Kn = lds + nxt*8192;
            const int k0n = kbase + (ti+1)*64;
            #pragma unroll
            for (int r = 0; r < 2; ++r) {
                int s = r*4 + w;
                int row = s*8 + lrow;
                gl2lds16(Kb  + base + (size_t)(k0n+row)*D_ + lc*8,    Kn + s*512);
                gl2lds16(Vtb + (size_t)(bh*D_ + row)*N_ + k0n + lc*8, Kn + 4096 + s*512);
            }
            wait_vm4();
        } else {
            wait_vm0();
        }
        __builtin_amdgcn_s_barrier();      // tile ti visible to all waves

        ufrag pfr[4];                      // A-frags for PV, kc = kt*2 + {lo,hi}
        #pragma unroll
        for (int kt = 0; kt < 2; ++kt) {
            // S^T tile: rows k (reg-dist), cols q (lane)
            ffrag16 s;
            #pragma unroll
            for (int r = 0; r < 16; ++r) s[r] = 0.f;
            int row = kt*32 + l31, r7 = row & 7;
            __builtin_amdgcn_s_setprio(1);
            #pragma unroll
            for (int kc = 0; kc < 4; ++kc) {
                bfrag kf = *(const bfrag*)(Kc + row*64 + ((kc*2 + hi) ^ r7)*8);
                s = __builtin_amdgcn_mfma_f32_32x32x16_bf16(kf, qf[kc], s, 0, 0, 0);
            }
            __builtin_amdgcn_s_setprio(0);
            // p = 2^s; trunc-pack to bf16 pairs (k even-adjacent)
            #pragma unroll
            for (int r = 0; r < 16; ++r)
                s[r] = __builtin_amdgcn_exp2f(s[r]);
            // group g (regs 4g..4g+3) holds k_local = 8g + 4hi + {0..3}
            unsigned q01_0 = pktrunc(s[0],  s[1]),  q23_0 = pktrunc(s[2],  s[3]);
            unsigned q01_1 = pktrunc(s[4],  s[5]),  q23_1 = pktrunc(s[6],  s[7]);
            unsigned q01_2 = pktrunc(s[8],  s[9]),  q23_2 = pktrunc(s[10], s[11]);
            unsigned q01_3 = pktrunc(s[12], s[13]), q23_3 = pktrunc(s[14], s[15]);
            // v_permlane32_swap: {a',b'} with a' = [a.lo32 | b.lo32],
            // b' = [a.hi32 | b.hi32] — exactly the lo/hi fragment exchange.
            uint2v e0 = __builtin_amdgcn_permlane32_swap(q01_0, q01_1, false, false);
            uint2v e1 = __builtin_amdgcn_permlane32_swap(q23_0, q23_1, false, false);
            uint2v e2 = __builtin_amdgcn_permlane32_swap(q01_2, q01_3, false, false);
            uint2v e3 = __builtin_amdgcn_permlane32_swap(q23_2, q23_3, false, false);
            ufrag lo, hif;
            lo[0]  = e0[0]; lo[1]  = e1[0]; lo[2]  = e0[1]; lo[3]  = e1[1];
            hif[0] = e2[0]; hif[1] = e3[0]; hif[2] = e2[1]; hif[3] = e3[1];
            pfr[kt*2]     = lo;            // k_local 0-15  (P[q][8hi+j] form)
            pfr[kt*2 + 1] = hif;           // k_local 16-31
        }

        // O += P V ; l += P 1  (consumes the same truncated P frags)
        __builtin_amdgcn_s_setprio(1);
        #pragma unroll
        for (int kc = 0; kc < 4; ++kc) {
            bfrag pf = __builtin_bit_cast(bfrag, pfr[kc]);
            #pragma unroll
            for (int dt = 0; dt < 2; ++dt) {
                int row = dt*32 + l31, r7 = row & 7;
                bfrag vf = *(const bfrag*)(Vc + row*64 + ((kc*2 + hi) ^ r7)*8);
                oacc[dt] = __builtin_amdgcn_mfma_f32_32x32x16_bf16(pf, vf, oacc[dt], 0, 0, 0);
            }
            lfr = __builtin_amdgcn_mfma_f32_32x32x16_bf16(pf, vones, lfr, 0, 0, 0);
        }
        __builtin_amdgcn_s_setprio(0);
        cur = nxt;                         // no trailing barrier (3-ring WAR-safe)
    }

    const int b = bh / HEADS, head = bh - b*HEADS;
    float* Op = Opart + (size_t)split * M_ * C_;
    float* lp = lpart + (size_t)split * (B_*HEADS) * N_;

    // lfr: every column (lane) holds l[q-row]; rows mapped like oacc
    if (l31 == 0) {
        #pragma unroll
        for (int r = 0; r < 16; ++r) {
            int n = q0 + w*32 + (r & 3) + 8*(r >> 2) + 4*hi;
            lp[bh*N_ + n] = lfr[r];
        }
    }

    #pragma unroll
    for (int dt = 0; dt < 2; ++dt)
        #pragma unroll
        for (int r = 0; r < 16; ++r) {
            int n = q0 + w*32 + (r & 3) + 8*(r >> 2) + 4*hi;
            int c = head*D_ + dt*32 + l31;
            Op[((size_t)b*N_ + n)*C_ + c] = oacc[dt][r];
        }
}

// ---------------------------------------------------------------------------
// Merge split-K partials: Ob = (sum_s O_s) / (sum_s l_s), bf16 out.
// ---------------------------------------------------------------------------
__global__ __launch_bounds__(256) void attn_merge(const float* __restrict__ Opart,
                                                  const float* __restrict__ lpart,
                                                  short* __restrict__ Ob) {
    int i = blockIdx.x * 256 + threadIdx.x;          // over M_*C_/4
    int m = i / (C_/4);
    int c = (i - m*(C_/4)) * 4;
    int b = m / N_, n = m - b*N_;
    int bh = b*HEADS + (c >> 6);
    float4 o0 = ((const float4*)Opart)[i];
    float4 o1 = ((const float4*)(Opart + (size_t)M_*C_))[i];
    float l = lpart[bh*N_ + n] + lpart[(B_*HEADS)*N_ + bh*N_ + n];
    float inv = 1.f / l;
    short4 o;
    o.x = f2bf((o0.x + o1.x) * inv);
    o.y = f2bf((o0.y + o1.y) * inv);
    o.z = f2bf((o0.z + o1.z) * inv);
    o.w = f2bf((o0.w + o1.w) * inv);
    ((short4*)Ob)[i] = o;
}

// ---------------------------------------------------------------------------
// Proj GEMM: out[m][f] = sum_c O[m][c]*w[f][c] + bias[f], fp32 out.
// Same 3-ring single-barrier pipeline + XCD swizzle (216 % 8 == 0).
// ---------------------------------------------------------------------------
__global__ __launch_bounds__(256) void proj_gemm(const short* __restrict__ Ab,
                                                 const short* __restrict__ wb,
                                                 const float* __restrict__ bias,
                                                 float* __restrict__ out) {
    __shared__ short As[3][128*32];
    __shared__ short Bs[3][128*32];
    const int t = threadIdx.x;
    const int w = t >> 6, lane = t & 63;
    const int quad = lane >> 4, l15 = lane & 15;
    const int wr = w >> 1, wc = w & 1;

    const int nwg = gridDim.x * gridDim.y;
    const int bid = blockIdx.y * gridDim.x + blockIdx.x;
    const int swz = (bid & 7) * (nwg >> 3) + (bid >> 3);
    const int m0 = (swz / gridDim.x) * 128, f0 = (swz % gridDim.x) * 128;

    const int srow = lane >> 2;
    const int skk  = (lane & 3) * 8;

    ffrag acc[4][4] = {};

    // prologue: issue K-step 0 into slot 0
    #pragma unroll
    for (int r = 0; r < 2; ++r) {
        int seg = r*4 + w;
        int row = seg*16 + srow;
        gl2lds16(Ab + (size_t)(m0+row)*C_ + skk, As[0] + seg*512);
        gl2lds16(wb + (size_t)(f0+row)*C_ + skk, Bs[0] + seg*512);
    }

    const int NKT = C_/32;                 // 24
    int cur = 0;
    for (int kt = 0; kt < NKT; ++kt) {
        int nxt = cur + 1; if (nxt == 3) nxt = 0;
        if (kt + 1 < NKT) {
            const int k0n = (kt+1)*32;
            #pragma unroll
            for (int r = 0; r < 2; ++r) {
                int seg = r*4 + w;
                int row = seg*16 + srow;
                gl2lds16(Ab + (size_t)(m0+row)*C_ + k0n + skk, As[nxt] + seg*512);
                gl2lds16(wb + (size_t)(f0+row)*C_ + k0n + skk, Bs[nxt] + seg*512);
            }
            wait_vm4();
        } else {
            wait_vm0();
        }
        __builtin_amdgcn_s_barrier();

        bfrag af[4], bf[4];
        #pragma unroll
        for (int i = 0; i < 4; ++i)
            af[i] = *(const bfrag*)(As[cur] + (wr*64 + i*16 + l15)*32 + quad*8);
        #pragma unroll
        for (int j = 0; j < 4; ++j)
            bf[j] = *(const bfrag*)(Bs[cur] + (wc*64 + j*16 + l15)*32 + quad*8);
        #pragma unroll
        for (int i = 0; i < 4; ++i)
            #pragma unroll
            for (int j = 0; j < 4; ++j)
                acc[i][j] = __builtin_amdgcn_mfma_f32_16x16x32_bf16(af[i], bf[j], acc[i][j], 0, 0, 0);
        cur = nxt;
    }

    #pragma unroll
    for (int i = 0; i < 4; ++i) {
        int mbase = m0 + wr*64 + i*16 + quad*4;
        #pragma unroll
        for (int j = 0; j < 4; ++j) {
            int f = f0 + wc*64 + j*16 + l15;
            float bv = bias[f];
            #pragma unroll
            for (int r = 0; r < 4; ++r)
                out[(size_t)(mbase + r)*C_ + f] = acc[i][j][r] + bv;
        }
    }
}

// ---------------------------------------------------------------------------
extern "C" void kernel_launch(void* const* d_in, const int* in_sizes, int n_in,
                              void* d_out, int out_size, void* d_ws, size_t ws_size,
                              hipStream_t stream) {
    const float* x      = (const float*)d_in[0];
    const float* qkv_w  = (const float*)d_in[3];
    const float* proj_w = (const float*)d_in[4];
    const float* proj_b = (const float*)d_in[5];
    float* out = (float*)d_out;

    const size_t nx = (size_t)M_ * C_;        // 3,538,944
    const size_t nq = (size_t)F3 * C_;        // 1,769,472
    const size_t np = (size_t)C_ * C_;        //   589,824
    short* xb  = (short*)d_ws;
    short* qwb = xb  + nx;
    short* pwb = qwb + nq;
    short* Qb  = pwb + np;
    short* Kb  = Qb  + nx;
    short* Vtb = Kb  + nx;
    short* Ob  = Vtb + nx;
    float* Opart = (float*)(Ob + nx);                       // SPLITS * M_*C_
    float* lpart = Opart + (size_t)SPLITS * M_ * C_;        // SPLITS * 24*N_

    const int ncast4 = (int)((nx + nq + np) / 4);
    cast_all<<<dim3((ncast4 + 255)/256), 256, 0, stream>>>(x, qkv_w, proj_w, xb);

    qkv_gemm<<<dim3(F3/128, M_/128), 256, 0, stream>>>(xb, qwb, Qb, Kb, Vtb);
    attn_mfma<<<dim3(N_/128, B_*HEADS, SPLITS), 256, 0, stream>>>(Qb, Kb, Vtb, Opart, lpart);
    attn_merge<<<dim3(((int)(nx/4) + 255)/256), 256, 0, stream>>>(Opart, lpart, Ob);
    proj_gemm<<<dim3(C_/128, M_/128), 256, 0, stream>>>(Ob, pwb, proj_b, out);
}

// Round 8
// 193.313 us; speedup vs baseline: 1.0239x; 1.0239x over previous
//
#include <hip/hip_runtime.h>

#define B_    2
#define N_    2304
#define C_    768
#define HEADS 12
#define D_    64
#define F3    2304
#define M_    (B_*N_)        // 4608
#define SPLITS 2
#define KSPAN (N_/SPLITS)    // 1152
// SCALE(0.125) * log2(e) folded into Q at qkv epilogue:
#define QSCALE 0.18033688011112042f

typedef __attribute__((ext_vector_type(8)))  short bfrag;    // 8 x bf16 (4 VGPR)
typedef __attribute__((ext_vector_type(4)))  float ffrag;    // 16x16 acc
typedef __attribute__((ext_vector_type(16))) float ffrag16;  // 32x32 acc
typedef __attribute__((ext_vector_type(4)))  unsigned ufrag; // 4 x b32 = 8 bf16
typedef __attribute__((ext_vector_type(2)))  unsigned uint2v;

__device__ __forceinline__ short f2bf(float f) {
    unsigned u = __float_as_uint(f);
    u += 0x7fff + ((u >> 16) & 1);          // RNE
    return (short)(u >> 16);
}

__device__ __forceinline__ void gl2lds16(const void* g, void* l) {
    __builtin_amdgcn_global_load_lds(
        (const __attribute__((address_space(1))) void*)g,
        (__attribute__((address_space(3))) void*)l, 16, 0, 0);
}

// Counted waits (T4): never drain the just-issued prefetch. "memory"
// clobber keeps ds_read/global ops from crossing.
__device__ __forceinline__ void wait_vm4() { asm volatile("s_waitcnt vmcnt(4)" ::: "memory"); }
__device__ __forceinline__ void wait_vm0() { asm volatile("s_waitcnt vmcnt(0)" ::: "memory"); }

// trunc-pack two fp32 -> (bf16(a) low | bf16(b) high) in ONE v_perm_b32.
// bias-safe here because numerator (PV) and denominator (ones-MFMA) both
// consume the same truncated fragments -> common bias cancels in the ratio.
__device__ __forceinline__ unsigned pktrunc(float a, float b) {
    return __builtin_amdgcn_perm(__float_as_uint(a), __float_as_uint(b),
                                 0x03020706u);
}

// ---------------------------------------------------------------------------
// Fused fp32 -> bf16 cast of x, qkv_w, proj_w (dsts contiguous in ws).
// ---------------------------------------------------------------------------
__global__ __launch_bounds__(256) void cast_all(const float* __restrict__ x,
                                                const float* __restrict__ qw,
                                                const float* __restrict__ pw,
                                                short* __restrict__ dst) {
    const int nx4 = (M_*C_)/4, nq4 = (F3*C_)/4, np4 = (C_*C_)/4;
    int i = blockIdx.x * 256 + threadIdx.x;
    if (i >= nx4 + nq4 + np4) return;
    const float* src; int off;
    if (i < nx4)            { src = x;  off = i; }
    else if (i < nx4 + nq4) { src = qw; off = i - nx4; }
    else                    { src = pw; off = i - nx4 - nq4; }
    float4 v = ((const float4*)src)[off];
    short4 o;
    o.x = f2bf(v.x); o.y = f2bf(v.y); o.z = f2bf(v.z); o.w = f2bf(v.w);
    ((short4*)dst)[i] = o;
}

// ---------------------------------------------------------------------------
// QKV GEMM: qkv[m][f] = sum_c x[m][c]*w[f][c]  (NT), m97 structure
// + 2-phase double-buffer with COUNTED vmcnt (T4): per K-step
//   {issue 4 loads(t+1); vmcnt(4); s_barrier; ds_read+MFMA(t); s_barrier}.
// + XCD-chunked blockIdx swizzle (648 % 8 == 0 -> bijective).
// Q stored pre-scaled by SCALE*log2e; V stored transposed [bh,d,n].
// (3-ring single-barrier variant measured WORSE in r7: LDS 48K cut
//  occupancy; reverted to this r5/r6 form.)
// ---------------------------------------------------------------------------
__global__ __launch_bounds__(256) void qkv_gemm(const short* __restrict__ xb,
                                                const short* __restrict__ wb,
                                                short* __restrict__ Qb,
                                                short* __restrict__ Kb,
                                                short* __restrict__ Vtb) {
    __shared__ short As[2][128*32];
    __shared__ short Bs[2][128*32];
    const int t = threadIdx.x;
    const int w = t >> 6, lane = t & 63;
    const int quad = lane >> 4, l15 = lane & 15;
    const int wr = w >> 1, wc = w & 1;

    const int nwg = gridDim.x * gridDim.y;
    const int bid = blockIdx.y * gridDim.x + blockIdx.x;
    const int swz = (bid & 7) * (nwg >> 3) + (bid >> 3);
    const int m0 = (swz / gridDim.x) * 128, f0 = (swz % gridDim.x) * 128;

    const int srow = lane >> 2;            // row within 16-row segment
    const int skk  = (lane & 3) * 8;       // bf16 offset within 32-col row

    ffrag acc[4][4] = {};

    // prologue: issue K-step 0 into buffer 0 (4 loads, not waited here)
    #pragma unroll
    for (int r = 0; r < 2; ++r) {
        int seg = r*4 + w;
        int row = seg*16 + srow;
        gl2lds16(xb + (size_t)(m0+row)*C_ + skk, As[0] + seg*512);
        gl2lds16(wb + (size_t)(f0+row)*C_ + skk, Bs[0] + seg*512);
    }

    const int NKT = C_/32;                 // 24
    for (int kt = 0; kt < NKT; ++kt) {
        const int cur = kt & 1;
        if (kt + 1 < NKT) {                // prefetch next K-step into buf^1
            const int k0n = (kt+1)*32;
            #pragma unroll
            for (int r = 0; r < 2; ++r) {
                int seg = r*4 + w;
                int row = seg*16 + srow;
                gl2lds16(xb + (size_t)(m0+row)*C_ + k0n + skk, As[cur^1] + seg*512);
                gl2lds16(wb + (size_t)(f0+row)*C_ + k0n + skk, Bs[cur^1] + seg*512);
            }
            wait_vm4();                    // tile kt landed; kt+1 in flight
        } else {
            wait_vm0();
        }
        __builtin_amdgcn_s_barrier();      // tile kt visible to all waves

        bfrag af[4], bf[4];
        #pragma unroll
        for (int i = 0; i < 4; ++i)
            af[i] = *(const bfrag*)(As[cur] + (wr*64 + i*16 + l15)*32 + quad*8);
        #pragma unroll
        for (int j = 0; j < 4; ++j)
            bf[j] = *(const bfrag*)(Bs[cur] + (wc*64 + j*16 + l15)*32 + quad*8);
        #pragma unroll
        for (int i = 0; i < 4; ++i)
            #pragma unroll
            for (int j = 0; j < 4; ++j)
                acc[i][j] = __builtin_amdgcn_mfma_f32_16x16x32_bf16(af[i], bf[j], acc[i][j], 0, 0, 0);
        __builtin_amdgcn_s_barrier();      // reads of buf[cur] done before overwrite
    }

    const int b   = m0 / N_;
    const int seg = f0 + wc*64;
    const int which = seg / C_;                  // 0=Q 1=K 2=V
    const int head  = (seg - which*C_) >> 6;
    const int bh    = b*HEADS + head;
    const int nbase = (m0 - b*N_) + wr*64 + quad*4;

    if (which == 0) {
        #pragma unroll
        for (int i = 0; i < 4; ++i) {
            int n0 = nbase + i*16;
            #pragma unroll
            for (int j = 0; j < 4; ++j) {
                int d = j*16 + l15;
                #pragma unroll
                for (int r = 0; r < 4; ++r)
                    Qb[((size_t)bh*N_ + n0 + r)*D_ + d] = f2bf(acc[i][j][r] * QSCALE);
            }
        }
    } else if (which == 1) {
        #pragma unroll
        for (int i = 0; i < 4; ++i) {
            int n0 = nbase + i*16;
            #pragma unroll
            for (int j = 0; j < 4; ++j) {
                int d = j*16 + l15;
                #pragma unroll
                for (int r = 0; r < 4; ++r)
                    Kb[((size_t)bh*N_ + n0 + r)*D_ + d] = f2bf(acc[i][j][r]);
            }
        }
    } else {
        #pragma unroll
        for (int i = 0; i < 4; ++i) {
            int n0 = nbase + i*16;
            #pragma unroll
            for (int j = 0; j < 4; ++j) {
                int d = j*16 + l15;
                short4 vv;
                vv.x = f2bf(acc[i][j][0]);
                vv.y = f2bf(acc[i][j][1]);
                vv.z = f2bf(acc[i][j][2]);
                vv.w = f2bf(acc[i][j][3]);
                *(short4*)(Vtb + ((size_t)bh*D_ + d)*N_ + n0) = vv;
            }
        }
    }
}

// ===========================================================================
// attn helpers (all register-level; constant indices only — rule #20)
// ===========================================================================

// QK^T for one kt (32 k-rows) + exp2 + trunc-pack + permlane32_swap.
// Outputs u0 (kc = kt*2: k_local 0-15 of this kt) and u1 (kc = kt*2+1).
__device__ __forceinline__ void qkpack(const short* Kc, const bfrag* qf,
                                       int kt, int l31, int hi,
                                       ufrag& u0, ufrag& u1) {
    ffrag16 s;
    #pragma unroll
    for (int r = 0; r < 16; ++r) s[r] = 0.f;
    int row = kt*32 + l31, r7 = row & 7;
    __builtin_amdgcn_s_setprio(1);
    #pragma unroll
    for (int kc = 0; kc < 4; ++kc) {
        bfrag kf = *(const bfrag*)(Kc + row*64 + ((kc*2 + hi) ^ r7)*8);
        s = __builtin_amdgcn_mfma_f32_32x32x16_bf16(kf, qf[kc], s, 0, 0, 0);
    }
    __builtin_amdgcn_s_setprio(0);
    #pragma unroll
    for (int r = 0; r < 16; ++r)
        s[r] = __builtin_amdgcn_exp2f(s[r]);
    unsigned q01_0 = pktrunc(s[0],  s[1]),  q23_0 = pktrunc(s[2],  s[3]);
    unsigned q01_1 = pktrunc(s[4],  s[5]),  q23_1 = pktrunc(s[6],  s[7]);
    unsigned q01_2 = pktrunc(s[8],  s[9]),  q23_2 = pktrunc(s[10], s[11]);
    unsigned q01_3 = pktrunc(s[12], s[13]), q23_3 = pktrunc(s[14], s[15]);
    uint2v e0 = __builtin_amdgcn_permlane32_swap(q01_0, q01_1, false, false);
    uint2v e1 = __builtin_amdgcn_permlane32_swap(q23_0, q23_1, false, false);
    uint2v e2 = __builtin_amdgcn_permlane32_swap(q01_2, q01_3, false, false);
    uint2v e3 = __builtin_amdgcn_permlane32_swap(q23_2, q23_3, false, false);
    ufrag lo, hif;
    lo[0]  = e0[0]; lo[1]  = e1[0]; lo[2]  = e0[1]; lo[3]  = e1[1];
    hif[0] = e2[0]; hif[1] = e3[0]; hif[2] = e2[1]; hif[3] = e3[1];
    u0 = lo; u1 = hif;
}

// PV + l for one kt, V from LDS (current tile's slot — valid).
__device__ __forceinline__ void pv_lds(ufrag u0, ufrag u1, const short* Vc,
                                       int kt, int l31, int hi, bfrag vones,
                                       ffrag16& o0, ffrag16& o1, ffrag16& lf) {
    int r0 = l31, r7a = r0 & 7;
    int r1 = 32 + l31, r7b = r1 & 7;
    bfrag p0 = __builtin_bit_cast(bfrag, u0);
    bfrag p1 = __builtin_bit_cast(bfrag, u1);
    int kcA = kt*2, kcB = kt*2 + 1;
    bfrag vA0 = *(const bfrag*)(Vc + r0*64 + ((kcA*2 + hi) ^ r7a)*8);
    bfrag vA1 = *(const bfrag*)(Vc + r1*64 + ((kcA*2 + hi) ^ r7b)*8);
    bfrag vB0 = *(const bfrag*)(Vc + r0*64 + ((kcB*2 + hi) ^ r7a)*8);
    bfrag vB1 = *(const bfrag*)(Vc + r1*64 + ((kcB*2 + hi) ^ r7b)*8);
    o0 = __builtin_amdgcn_mfma_f32_32x32x16_bf16(p0, vA0, o0, 0, 0, 0);
    o1 = __builtin_amdgcn_mfma_f32_32x32x16_bf16(p0, vA1, o1, 0, 0, 0);
    lf = __builtin_amdgcn_mfma_f32_32x32x16_bf16(p0, vones, lf, 0, 0, 0);
    o0 = __builtin_amdgcn_mfma_f32_32x32x16_bf16(p1, vB0, o0, 0, 0, 0);
    o1 = __builtin_amdgcn_mfma_f32_32x32x16_bf16(p1, vB1, o1, 0, 0, 0);
    lf = __builtin_amdgcn_mfma_f32_32x32x16_bf16(p1, vones, lf, 0, 0, 0);
}

// PV + l for the DEFERRED kt: P and V all in registers (LDS slot may be
// mid-overwrite by the in-flight prefetch — regs are the safe copy).
__device__ __forceinline__ void pv_reg(ufrag u0, ufrag u1,
                                       bfrag v0, bfrag v1, bfrag v2, bfrag v3,
                                       bfrag vones,
                                       ffrag16& o0, ffrag16& o1, ffrag16& lf) {
    bfrag p0 = __builtin_bit_cast(bfrag, u0);
    bfrag p1 = __builtin_bit_cast(bfrag, u1);
    o0 = __builtin_amdgcn_mfma_f32_32x32x16_bf16(p0, v0, o0, 0, 0, 0);
    o1 = __builtin_amdgcn_mfma_f32_32x32x16_bf16(p0, v1, o1, 0, 0, 0);
    lf = __builtin_amdgcn_mfma_f32_32x32x16_bf16(p0, vones, lf, 0, 0, 0);
    o0 = __builtin_amdgcn_mfma_f32_32x32x16_bf16(p1, v2, o0, 0, 0, 0);
    o1 = __builtin_amdgcn_mfma_f32_32x32x16_bf16(p1, v3, o1, 0, 0, 0);
    lf = __builtin_amdgcn_mfma_f32_32x32x16_bf16(p1, vones, lf, 0, 0, 0);
}

// Load the 4 V-frags of one kt into registers (before the trailing barrier,
// while the slot is still valid).
__device__ __forceinline__ void vload4(const short* Vc, int kt, int l31, int hi,
                                       bfrag& v0, bfrag& v1, bfrag& v2, bfrag& v3) {
    int r0 = l31, r7a = r0 & 7;
    int r1 = 32 + l31, r7b = r1 & 7;
    int kcA = kt*2, kcB = kt*2 + 1;
    v0 = *(const bfrag*)(Vc + r0*64 + ((kcA*2 + hi) ^ r7a)*8);
    v1 = *(const bfrag*)(Vc + r1*64 + ((kcA*2 + hi) ^ r7b)*8);
    v2 = *(const bfrag*)(Vc + r0*64 + ((kcB*2 + hi) ^ r7a)*8);
    v3 = *(const bfrag*)(Vc + r1*64 + ((kcB*2 + hi) ^ r7b)*8);
}

// ---------------------------------------------------------------------------
// Flash attention, 32x32x16 bf16 MFMA, no-max softmax, split-K over grid.z.
// Round-6 base (2-slot 32 KiB K/V double-buffer, counted-vmcnt, 2 barriers,
// ones-MFMA l, grid reorder + XCD swizzle) + T15 HALF-TILE PV DEFERRAL:
// PV(kt) runs during the NEXT kt's QK/exp/pack region, so each wave issues
// {QK MFMAs, deferred-PV MFMAs} back-to-back with exp2/pack VALU filling
// between — MFMA and VALU pipes busy simultaneously from one wave (the
// ~35% no-issue gap was the strict exp->pack->PV serial chain).
// Deferred state crosses the tile boundary as registers (2 ufrag P +
// 4 bfrag V = 24 VGPR) because its LDS slot is overwritten by the next
// prefetch. Every kt is PV'd exactly once; epilogue drains the last.
// LDS rows 128B, XOR-swizzled: chunk c of row r lives at (c ^ (r&7))*16B.
// 32x32 C layout: col = lane&31, row = (reg&3) + 8*(reg>>2) + 4*(lane>>5).
// ---------------------------------------------------------------------------
__global__ __launch_bounds__(256, 4) void attn_mfma(const short* __restrict__ Qb,
                                                    const short* __restrict__ Kb,
                                                    const short* __restrict__ Vtb,
                                                    float* __restrict__ Opart,
                                                    float* __restrict__ lpart) {
    // 32 KiB total: slot s at lds + s*8192 shorts (K 4096 | V 4096).
    __shared__ short lds[16384];
    const int t = threadIdx.x;
    const int w = t >> 6, lane = t & 63;
    const int l31 = lane & 31, hi = lane >> 5;

    // XCD-chunk swizzle over the (qtile, bh) plane: fid is qtile-fastest.
    const int nwg = gridDim.x * gridDim.y;            // 432
    const int fid = blockIdx.y * gridDim.x + blockIdx.x;
    const int swz = (fid & 7) * (nwg >> 3) + (fid >> 3);
    const int bh  = swz / gridDim.x;
    const int q0  = (swz - bh * gridDim.x) * 128;

    const int split = blockIdx.z;
    const int kbase = split * KSPAN;
    const size_t base = (size_t)bh * N_ * D_;
    const int lrow = lane >> 3;            // row within 8-row segment
    const int lc   = (lane & 7) ^ lrow;    // swizzled source chunk

    short* Qs = lds + 8192;                // overlays slot 1

    // prologue: stage Q tile (128 x 64) into slot1 region, K/V tile 0 into slot0
    #pragma unroll
    for (int r = 0; r < 4; ++r) {
        int s = r*4 + w;
        gl2lds16(Qb + base + (size_t)(q0 + s*8 + lrow)*D_ + lc*8, Qs + s*512);
    }
    #pragma unroll
    for (int r = 0; r < 2; ++r) {
        int s = r*4 + w;
        int row = s*8 + lrow;
        gl2lds16(Kb  + base + (size_t)(kbase+row)*D_ + lc*8,    lds + s*512);
        gl2lds16(Vtb + (size_t)(bh*D_ + row)*N_ + kbase + lc*8, lds + 4096 + s*512);
    }
    __syncthreads();                       // Q + tile0 staged (full drain, once)

    // hoist Q B-frags (loop-invariant)
    bfrag qf[4];
    {
        int row = w*32 + l31, r7 = row & 7;
        #pragma unroll
        for (int kc = 0; kc < 4; ++kc)
            qf[kc] = *(const bfrag*)(Qs + row*64 + ((kc*2 + hi) ^ r7)*8);
    }
    __syncthreads();                       // Q-frag reads done before slot1 reuse

    // ones B-frag for the l (row-sum) MFMA
    bfrag vones;
    #pragma unroll
    for (int j = 0; j < 8; ++j) vones[j] = (short)0x3f80;

    ffrag16 oacc0, oacc1, lfr;
    #pragma unroll
    for (int r = 0; r < 16; ++r) { oacc0[r] = 0.f; oacc1[r] = 0.f; lfr[r] = 0.f; }

    const int NT = KSPAN / 64;             // 18

    // deferred state (kt1 of the previous tile)
    ufrag pP0, pP1;
    bfrag vP0, vP1, vP2, vP3;

    // ---- prime: tile 0 (slot 0); kt0 PV'd in place, kt1 deferred ----
    {
        // issue stage(tile 1) -> slot 1 (overwrites Q region; qf already hoisted)
        const int k0n = kbase + 64;
        #pragma unroll
        for (int r = 0; r < 2; ++r) {
            int s = r*4 + w;
            int row = s*8 + lrow;
            gl2lds16(Kb  + base + (size_t)(k0n+row)*D_ + lc*8,    lds + 8192 + s*512);
            gl2lds16(Vtb + (size_t)(bh*D_ + row)*N_ + k0n + lc*8, lds + 12288 + s*512);
        }
        const short* Kc = lds;
        const short* Vc = lds + 4096;
        ufrag a0, a1;
        qkpack(Kc, qf, 0, l31, hi, a0, a1);
        __builtin_amdgcn_s_setprio(1);
        pv_lds(a0, a1, Vc, 0, l31, hi, vones, oacc0, oacc1, lfr);
        __builtin_amdgcn_s_setprio(0);
        qkpack(Kc, qf, 1, l31, hi, pP0, pP1);
        vload4(Vc, 1, l31, hi, vP0, vP1, vP2, vP3);
        __builtin_amdgcn_s_barrier();      // tile0 reads done before slot0 reuse
    }

    // ---- tiles 1..NT-1 ----
    for (int ti = 1; ti < NT; ++ti) {
        const int cur = ti & 1;
        const short* Kc = lds + cur*8192;
        const short* Vc = Kc + 4096;

        if (ti + 1 < NT) {                 // prefetch next tile into slot cur^1
            short* Kn = lds + (cur^1)*8192;
            const int k0n = kbase + (ti+1)*64;
            #pragma unroll
            for (int r = 0; r < 2; ++r) {
                int s = r*4 + w;
                int row = s*8 + lrow;
                gl2lds16(Kb  + base + (size_t)(k0n+row)*D_ + lc*8,    Kn + s*512);
                gl2lds16(Vtb + (size_t)(bh*D_ + row)*N_ + k0n + lc*8, Kn + 4096 + s*512);
            }
            wait_vm4();
        } else {
            wait_vm0();
        }
        __builtin_amdgcn_s_barrier();      // tile ti visible

        // kt0: QK, then {deferred PV (reg-only, independent) | exp/pack}
        ufrag a0, a1;
        qkpack(Kc, qf, 0, l31, hi, a0, a1);
        __builtin_amdgcn_s_setprio(1);
        pv_reg(pP0, pP1, vP0, vP1, vP2, vP3, vones, oacc0, oacc1, lfr);
        pv_lds(a0, a1, Vc, 0, l31, hi, vones, oacc0, oacc1, lfr);
        __builtin_amdgcn_s_setprio(0);
        // kt1: QK/exp/pack, then save P + V to regs for next iteration
        qkpack(Kc, qf, 1, l31, hi, pP0, pP1);
        vload4(Vc, 1, l31, hi, vP0, vP1, vP2, vP3);
        __builtin_amdgcn_s_barrier();      // tile ti reads done before slot reuse
    }

    // epilogue: drain the last deferred kt
    pv_reg(pP0, pP1, vP0, vP1, vP2, vP3, vones, oacc0, oacc1, lfr);

    const int b = bh / HEADS, head = bh - b*HEADS;
    float* Op = Opart + (size_t)split * M_ * C_;
    float* lp = lpart + (size_t)split * (B_*HEADS) * N_;

    // lfr: every column (lane) holds l[q-row]; rows mapped like oacc
    if (l31 == 0) {
        #pragma unroll
        for (int r = 0; r < 16; ++r) {
            int n = q0 + w*32 + (r & 3) + 8*(r >> 2) + 4*hi;
            lp[bh*N_ + n] = lfr[r];
        }
    }

    #pragma unroll
    for (int r = 0; r < 16; ++r) {
        int n = q0 + w*32 + (r & 3) + 8*(r >> 2) + 4*hi;
        int c = head*D_ + l31;
        Op[((size_t)b*N_ + n)*C_ + c] = oacc0[r];
        Op[((size_t)b*N_ + n)*C_ + c + 32] = oacc1[r];
    }
}

// ---------------------------------------------------------------------------
// Merge split-K partials: Ob = (sum_s O_s) / (sum_s l_s), bf16 out.
// ---------------------------------------------------------------------------
__global__ __launch_bounds__(256) void attn_merge(const float* __restrict__ Opart,
                                                  const float* __restrict__ lpart,
                                                  short* __restrict__ Ob) {
    int i = blockIdx.x * 256 + threadIdx.x;          // over M_*C_/4
    int m = i / (C_/4);
    int c = (i - m*(C_/4)) * 4;
    int b = m / N_, n = m - b*N_;
    int bh = b*HEADS + (c >> 6);
    float4 o0 = ((const float4*)Opart)[i];
    float4 o1 = ((const float4*)(Opart + (size_t)M_*C_))[i];
    float l = lpart[bh*N_ + n] + lpart[(B_*HEADS)*N_ + bh*N_ + n];
    float inv = 1.f / l;
    short4 o;
    o.x = f2bf((o0.x + o1.x) * inv);
    o.y = f2bf((o0.y + o1.y) * inv);
    o.z = f2bf((o0.z + o1.z) * inv);
    o.w = f2bf((o0.w + o1.w) * inv);
    ((short4*)Ob)[i] = o;
}

// ---------------------------------------------------------------------------
// Proj GEMM: out[m][f] = sum_c O[m][c]*w[f][c] + bias[f], fp32 out.
// Same counted-vmcnt pipeline + XCD swizzle (216 blocks % 8 == 0).
// ---------------------------------------------------------------------------
__global__ __launch_bounds__(256) void proj_gemm(const short* __restrict__ Ab,
                                                 const short* __restrict__ wb,
                                                 const float* __restrict__ bias,
                                                 float* __restrict__ out) {
    __shared__ short As[2][128*32];
    __shared__ short Bs[2][128*32];
    const int t = threadIdx.x;
    const int w = t >> 6, lane = t & 63;
    const int quad = lane >> 4, l15 = lane & 15;
    const int wr = w >> 1, wc = w & 1;

    const int nwg = gridDim.x * gridDim.y;
    const int bid = blockIdx.y * gridDim.x + blockIdx.x;
    const int swz = (bid & 7) * (nwg >> 3) + (bid >> 3);
    const int m0 = (swz / gridDim.x) * 128, f0 = (swz % gridDim.x) * 128;

    const int srow = lane >> 2;
    const int skk  = (lane & 3) * 8;

    ffrag acc[4][4] = {};

    // prologue: issue K-step 0 into buffer 0
    #pragma unroll
    for (int r = 0; r < 2; ++r) {
        int seg = r*4 + w;
        int row = seg*16 + srow;
        gl2lds16(Ab + (size_t)(m0+row)*C_ + skk, As[0] + seg*512);
        gl2lds16(wb + (size_t)(f0+row)*C_ + skk, Bs[0] + seg*512);
    }

    const int NKT = C_/32;                 // 24
    for (int kt = 0; kt < NKT; ++kt) {
        const int cur = kt & 1;
        if (kt + 1 < NKT) {
            const int k0n = (kt+1)*32;
            #pragma unroll
            for (int r = 0; r < 2; ++r) {
                int seg = r*4 + w;
                int row = seg*16 + srow;
                gl2lds16(Ab + (size_t)(m0+row)*C_ + k0n + skk, As[cur^1] + seg*512);
                gl2lds16(wb + (size_t)(f0+row)*C_ + k0n + skk, Bs[cur^1] + seg*512);
            }
            wait_vm4();
        } else {
            wait_vm0();
        }
        __builtin_amdgcn_s_barrier();

        bfrag af[4], bf[4];
        #pragma unroll
        for (int i = 0; i < 4; ++i)
            af[i] = *(const bfrag*)(As[cur] + (wr*64 + i*16 + l15)*32 + quad*8);
        #pragma unroll
        for (int j = 0; j < 4; ++j)
            bf[j] = *(const bfrag*)(Bs[cur] + (wc*64 + j*16 + l15)*32 + quad*8);
        #pragma unroll
        for (int i = 0; i < 4; ++i)
            #pragma unroll
            for (int j = 0; j < 4; ++j)
                acc[i][j] = __builtin_amdgcn_mfma_f32_16x16x32_bf16(af[i], bf[j], acc[i][j], 0, 0, 0);
        __builtin_amdgcn_s_barrier();
    }

    #pragma unroll
    for (int i = 0; i < 4; ++i) {
        int mbase = m0 + wr*64 + i*16 + quad*4;
        #pragma unroll
        for (int j = 0; j < 4; ++j) {
            int f = f0 + wc*64 + j*16 + l15;
            float bv = bias[f];
            #pragma unroll
            for (int r = 0; r < 4; ++r)
                out[(size_t)(mbase + r)*C_ + f] = acc[i][j][r] + bv;
        }
    }
}

// ---------------------------------------------------------------------------
extern "C" void kernel_launch(void* const* d_in, const int* in_sizes, int n_in,
                              void* d_out, int out_size, void* d_ws, size_t ws_size,
                              hipStream_t stream) {
    const float* x      = (const float*)d_in[0];
    const float* qkv_w  = (const float*)d_in[3];
    const float* proj_w = (const float*)d_in[4];
    const float* proj_b = (const float*)d_in[5];
    float* out = (float*)d_out;

    const size_t nx = (size_t)M_ * C_;        // 3,538,944
    const size_t nq = (size_t)F3 * C_;        // 1,769,472
    const size_t np = (size_t)C_ * C_;        //   589,824
    short* xb  = (short*)d_ws;
    short* qwb = xb  + nx;
    short* pwb = qwb + nq;
    short* Qb  = pwb + np;
    short* Kb  = Qb  + nx;
    short* Vtb = Kb  + nx;
    short* Ob  = Vtb + nx;
    float* Opart = (float*)(Ob + nx);                       // SPLITS * M_*C_
    float* lpart = Opart + (size_t)SPLITS * M_ * C_;        // SPLITS * 24*N_

    const int ncast4 = (int)((nx + nq + np) / 4);
    cast_all<<<dim3((ncast4 + 255)/256), 256, 0, stream>>>(x, qkv_w, proj_w, xb);

    qkv_gemm<<<dim3(F3/128, M_/128), 256, 0, stream>>>(xb, qwb, Qb, Kb, Vtb);
    attn_mfma<<<dim3(N_/128, B_*HEADS, SPLITS), 256, 0, stream>>>(Qb, Kb, Vtb, Opart, lpart);
    attn_merge<<<dim3(((int)(nx/4) + 255)/256), 256, 0, stream>>>(Opart, lpart, Ob);
    proj_gemm<<<dim3(C_/128, M_/128), 256, 0, stream>>>(Ob, pwb, proj_b, out);
}

// Round 9
// 191.066 us; speedup vs baseline: 1.0360x; 1.0118x over previous
//
#include <hip/hip_runtime.h>

#define B_    2
#define N_    2304
#define C_    768
#define HEADS 12
#define D_    64
#define F3    2304
#define M_    (B_*N_)        // 4608
#define SPLITS 2
#define KSPAN (N_/SPLITS)    // 1152
// SCALE(0.125) * log2(e) folded into Q at qkv epilogue:
#define QSCALE 0.18033688011112042f

typedef __attribute__((ext_vector_type(8)))  short bfrag;    // 8 x bf16 (4 VGPR)
typedef __attribute__((ext_vector_type(4)))  float ffrag;    // 16x16 acc
typedef __attribute__((ext_vector_type(16))) float ffrag16;  // 32x32 acc
typedef __attribute__((ext_vector_type(4)))  unsigned ufrag; // 4 x b32 = 8 bf16
typedef __attribute__((ext_vector_type(2)))  unsigned uint2v;

__device__ __forceinline__ short f2bf(float f) {
    unsigned u = __float_as_uint(f);
    u += 0x7fff + ((u >> 16) & 1);          // RNE
    return (short)(u >> 16);
}

__device__ __forceinline__ void gl2lds16(const void* g, void* l) {
    __builtin_amdgcn_global_load_lds(
        (const __attribute__((address_space(1))) void*)g,
        (__attribute__((address_space(3))) void*)l, 16, 0, 0);
}

// Counted waits (T4): never drain in-flight prefetches. "memory" clobber
// keeps ds_read/global ops from crossing.
__device__ __forceinline__ void wait_vm8() { asm volatile("s_waitcnt vmcnt(8)" ::: "memory"); }
__device__ __forceinline__ void wait_vm4() { asm volatile("s_waitcnt vmcnt(4)" ::: "memory"); }
__device__ __forceinline__ void wait_vm0() { asm volatile("s_waitcnt vmcnt(0)" ::: "memory"); }

// trunc-pack two fp32 -> (bf16(a) low | bf16(b) high) in ONE v_perm_b32.
// bias-safe here because numerator (PV) and denominator (ones-MFMA) both
// consume the same truncated fragments -> common bias cancels in the ratio.
__device__ __forceinline__ unsigned pktrunc(float a, float b) {
    return __builtin_amdgcn_perm(__float_as_uint(a), __float_as_uint(b),
                                 0x03020706u);
}

// ---------------------------------------------------------------------------
// Fused fp32 -> bf16 cast of x, qkv_w, proj_w (dsts contiguous in ws).
// ---------------------------------------------------------------------------
__global__ __launch_bounds__(256) void cast_all(const float* __restrict__ x,
                                                const float* __restrict__ qw,
                                                const float* __restrict__ pw,
                                                short* __restrict__ dst) {
    const int nx4 = (M_*C_)/4, nq4 = (F3*C_)/4, np4 = (C_*C_)/4;
    int i = blockIdx.x * 256 + threadIdx.x;
    if (i >= nx4 + nq4 + np4) return;
    const float* src; int off;
    if (i < nx4)            { src = x;  off = i; }
    else if (i < nx4 + nq4) { src = qw; off = i - nx4; }
    else                    { src = pw; off = i - nx4 - nq4; }
    float4 v = ((const float4*)src)[off];
    short4 o;
    o.x = f2bf(v.x); o.y = f2bf(v.y); o.z = f2bf(v.z); o.w = f2bf(v.w);
    ((short4*)dst)[i] = o;
}

// ---------------------------------------------------------------------------
// QKV GEMM: qkv[m][f] = sum_c x[m][c]*w[f][c]  (NT), m97 structure
// + 3-slot LDS ring, TWO tiles in flight (AITER pattern, r8 diagnosis:
//   1-deep prefetch left each K-step stalled on its own ~900cy fetch at
//   only ~2.5 blocks/CU of TLP). Step t: issue loads(t+2) -> slot[(t+2)%3],
//   wait vmcnt(8) (drains ONLY tile t, issued two full iterations ago),
//   barrier, compute slot[t%3], barrier. Both barriers required for WAR
//   with 2-deep issue. LDS 48K caps at 3 blocks/CU = existing VGPR cap
//   (140 -> 3 waves/SIMD) -> no occupancy change.
// + XCD-chunked blockIdx swizzle (648 % 8 == 0 -> bijective).
// Q stored pre-scaled by SCALE*log2e; V stored transposed [bh,d,n].
// ---------------------------------------------------------------------------
__global__ __launch_bounds__(256) void qkv_gemm(const short* __restrict__ xb,
                                                const short* __restrict__ wb,
                                                short* __restrict__ Qb,
                                                short* __restrict__ Kb,
                                                short* __restrict__ Vtb) {
    __shared__ short As[3][128*32];
    __shared__ short Bs[3][128*32];
    const int t = threadIdx.x;
    const int w = t >> 6, lane = t & 63;
    const int quad = lane >> 4, l15 = lane & 15;
    const int wr = w >> 1, wc = w & 1;

    const int nwg = gridDim.x * gridDim.y;
    const int bid = blockIdx.y * gridDim.x + blockIdx.x;
    const int swz = (bid & 7) * (nwg >> 3) + (bid >> 3);
    const int m0 = (swz / gridDim.x) * 128, f0 = (swz % gridDim.x) * 128;

    const int srow = lane >> 2;            // row within 16-row segment
    const int skk  = (lane & 3) * 8;       // bf16 offset within 32-col row

    ffrag acc[4][4] = {};

    // prologue: issue K-steps 0,1 into slots 0,1 (8 loads/wave outstanding)
    #pragma unroll
    for (int r = 0; r < 2; ++r) {
        int seg = r*4 + w;
        int row = seg*16 + srow;
        gl2lds16(xb + (size_t)(m0+row)*C_ + skk, As[0] + seg*512);
        gl2lds16(wb + (size_t)(f0+row)*C_ + skk, Bs[0] + seg*512);
    }
    #pragma unroll
    for (int r = 0; r < 2; ++r) {
        int seg = r*4 + w;
        int row = seg*16 + srow;
        gl2lds16(xb + (size_t)(m0+row)*C_ + 32 + skk, As[1] + seg*512);
        gl2lds16(wb + (size_t)(f0+row)*C_ + 32 + skk, Bs[1] + seg*512);
    }

    const int NKT = C_/32;                 // 24
    int cur = 0;
    for (int kt = 0; kt < NKT; ++kt) {
        int pf = cur + 2; if (pf >= 3) pf -= 3;   // slot for kt+2
        if (kt + 2 < NKT) {                // issue 2-ahead, 12 outstanding
            const int k0n = (kt+2)*32;
            #pragma unroll
            for (int r = 0; r < 2; ++r) {
                int seg = r*4 + w;
                int row = seg*16 + srow;
                gl2lds16(xb + (size_t)(m0+row)*C_ + k0n + skk, As[pf] + seg*512);
                gl2lds16(wb + (size_t)(f0+row)*C_ + k0n + skk, Bs[pf] + seg*512);
            }
            wait_vm8();                    // drain tile kt only (2 iters old)
        } else if (kt + 1 < NKT) {
            wait_vm4();
        } else {
            wait_vm0();
        }
        __builtin_amdgcn_s_barrier();      // tile kt visible to all waves

        bfrag af[4], bf[4];
        #pragma unroll
        for (int i = 0; i < 4; ++i)
            af[i] = *(const bfrag*)(As[cur] + (wr*64 + i*16 + l15)*32 + quad*8);
        #pragma unroll
        for (int j = 0; j < 4; ++j)
            bf[j] = *(const bfrag*)(Bs[cur] + (wc*64 + j*16 + l15)*32 + quad*8);
        #pragma unroll
        for (int i = 0; i < 4; ++i)
            #pragma unroll
            for (int j = 0; j < 4; ++j)
                acc[i][j] = __builtin_amdgcn_mfma_f32_16x16x32_bf16(af[i], bf[j], acc[i][j], 0, 0, 0);
        __builtin_amdgcn_s_barrier();      // reads of slot[cur] done before overwrite
        cur = cur + 1; if (cur >= 3) cur = 0;
    }

    const int b   = m0 / N_;
    const int seg = f0 + wc*64;
    const int which = seg / C_;                  // 0=Q 1=K 2=V
    const int head  = (seg - which*C_) >> 6;
    const int bh    = b*HEADS + head;
    const int nbase = (m0 - b*N_) + wr*64 + quad*4;

    if (which == 0) {
        #pragma unroll
        for (int i = 0; i < 4; ++i) {
            int n0 = nbase + i*16;
            #pragma unroll
            for (int j = 0; j < 4; ++j) {
                int d = j*16 + l15;
                #pragma unroll
                for (int r = 0; r < 4; ++r)
                    Qb[((size_t)bh*N_ + n0 + r)*D_ + d] = f2bf(acc[i][j][r] * QSCALE);
            }
        }
    } else if (which == 1) {
        #pragma unroll
        for (int i = 0; i < 4; ++i) {
            int n0 = nbase + i*16;
            #pragma unroll
            for (int j = 0; j < 4; ++j) {
                int d = j*16 + l15;
                #pragma unroll
                for (int r = 0; r < 4; ++r)
                    Kb[((size_t)bh*N_ + n0 + r)*D_ + d] = f2bf(acc[i][j][r]);
            }
        }
    } else {
        #pragma unroll
        for (int i = 0; i < 4; ++i) {
            int n0 = nbase + i*16;
            #pragma unroll
            for (int j = 0; j < 4; ++j) {
                int d = j*16 + l15;
                short4 vv;
                vv.x = f2bf(acc[i][j][0]);
                vv.y = f2bf(acc[i][j][1]);
                vv.z = f2bf(acc[i][j][2]);
                vv.w = f2bf(acc[i][j][3]);
                *(short4*)(Vtb + ((size_t)bh*D_ + d)*N_ + n0) = vv;
            }
        }
    }
}

// ===========================================================================
// attn helpers (all register-level; constant indices only — rule #20)
// ===========================================================================

// QK^T for one kt (32 k-rows) + exp2 + trunc-pack + permlane32_swap.
// Outputs u0 (kc = kt*2: k_local 0-15 of this kt) and u1 (kc = kt*2+1).
__device__ __forceinline__ void qkpack(const short* Kc, const bfrag* qf,
                                       int kt, int l31, int hi,
                                       ufrag& u0, ufrag& u1) {
    ffrag16 s;
    #pragma unroll
    for (int r = 0; r < 16; ++r) s[r] = 0.f;
    int row = kt*32 + l31, r7 = row & 7;
    __builtin_amdgcn_s_setprio(1);
    #pragma unroll
    for (int kc = 0; kc < 4; ++kc) {
        bfrag kf = *(const bfrag*)(Kc + row*64 + ((kc*2 + hi) ^ r7)*8);
        s = __builtin_amdgcn_mfma_f32_32x32x16_bf16(kf, qf[kc], s, 0, 0, 0);
    }
    __builtin_amdgcn_s_setprio(0);
    #pragma unroll
    for (int r = 0; r < 16; ++r)
        s[r] = __builtin_amdgcn_exp2f(s[r]);
    unsigned q01_0 = pktrunc(s[0],  s[1]),  q23_0 = pktrunc(s[2],  s[3]);
    unsigned q01_1 = pktrunc(s[4],  s[5]),  q23_1 = pktrunc(s[6],  s[7]);
    unsigned q01_2 = pktrunc(s[8],  s[9]),  q23_2 = pktrunc(s[10], s[11]);
    unsigned q01_3 = pktrunc(s[12], s[13]), q23_3 = pktrunc(s[14], s[15]);
    uint2v e0 = __builtin_amdgcn_permlane32_swap(q01_0, q01_1, false, false);
    uint2v e1 = __builtin_amdgcn_permlane32_swap(q23_0, q23_1, false, false);
    uint2v e2 = __builtin_amdgcn_permlane32_swap(q01_2, q01_3, false, false);
    uint2v e3 = __builtin_amdgcn_permlane32_swap(q23_2, q23_3, false, false);
    ufrag lo, hif;
    lo[0]  = e0[0]; lo[1]  = e1[0]; lo[2]  = e0[1]; lo[3]  = e1[1];
    hif[0] = e2[0]; hif[1] = e3[0]; hif[2] = e2[1]; hif[3] = e3[1];
    u0 = lo; u1 = hif;
}

// PV + l for one kt, V from LDS (current tile's slot — valid).
__device__ __forceinline__ void pv_lds(ufrag u0, ufrag u1, const short* Vc,
                                       int kt, int l31, int hi, bfrag vones,
                                       ffrag16& o0, ffrag16& o1, ffrag16& lf) {
    int r0 = l31, r7a = r0 & 7;
    int r1 = 32 + l31, r7b = r1 & 7;
    bfrag p0 = __builtin_bit_cast(bfrag, u0);
    bfrag p1 = __builtin_bit_cast(bfrag, u1);
    int kcA = kt*2, kcB = kt*2 + 1;
    bfrag vA0 = *(const bfrag*)(Vc + r0*64 + ((kcA*2 + hi) ^ r7a)*8);
    bfrag vA1 = *(const bfrag*)(Vc + r1*64 + ((kcA*2 + hi) ^ r7b)*8);
    bfrag vB0 = *(const bfrag*)(Vc + r0*64 + ((kcB*2 + hi) ^ r7a)*8);
    bfrag vB1 = *(const bfrag*)(Vc + r1*64 + ((kcB*2 + hi) ^ r7b)*8);
    o0 = __builtin_amdgcn_mfma_f32_32x32x16_bf16(p0, vA0, o0, 0, 0, 0);
    o1 = __builtin_amdgcn_mfma_f32_32x32x16_bf16(p0, vA1, o1, 0, 0, 0);
    lf = __builtin_amdgcn_mfma_f32_32x32x16_bf16(p0, vones, lf, 0, 0, 0);
    o0 = __builtin_amdgcn_mfma_f32_32x32x16_bf16(p1, vB0, o0, 0, 0, 0);
    o1 = __builtin_amdgcn_mfma_f32_32x32x16_bf16(p1, vB1, o1, 0, 0, 0);
    lf = __builtin_amdgcn_mfma_f32_32x32x16_bf16(p1, vones, lf, 0, 0, 0);
}

// PV + l for the DEFERRED kt: P and V all in registers (LDS slot may be
// mid-overwrite by the in-flight prefetch — regs are the safe copy).
__device__ __forceinline__ void pv_reg(ufrag u0, ufrag u1,
                                       bfrag v0, bfrag v1, bfrag v2, bfrag v3,
                                       bfrag vones,
                                       ffrag16& o0, ffrag16& o1, ffrag16& lf) {
    bfrag p0 = __builtin_bit_cast(bfrag, u0);
    bfrag p1 = __builtin_bit_cast(bfrag, u1);
    o0 = __builtin_amdgcn_mfma_f32_32x32x16_bf16(p0, v0, o0, 0, 0, 0);
    o1 = __builtin_amdgcn_mfma_f32_32x32x16_bf16(p0, v1, o1, 0, 0, 0);
    lf = __builtin_amdgcn_mfma_f32_32x32x16_bf16(p0, vones, lf, 0, 0, 0);
    o0 = __builtin_amdgcn_mfma_f32_32x32x16_bf16(p1, v2, o0, 0, 0, 0);
    o1 = __builtin_amdgcn_mfma_f32_32x32x16_bf16(p1, v3, o1, 0, 0, 0);
    lf = __builtin_amdgcn_mfma_f32_32x32x16_bf16(p1, vones, lf, 0, 0, 0);
}

// Load the 4 V-frags of one kt into registers (before the trailing barrier,
// while the slot is still valid).
__device__ __forceinline__ void vload4(const short* Vc, int kt, int l31, int hi,
                                       bfrag& v0, bfrag& v1, bfrag& v2, bfrag& v3) {
    int r0 = l31, r7a = r0 & 7;
    int r1 = 32 + l31, r7b = r1 & 7;
    int kcA = kt*2, kcB = kt*2 + 1;
    v0 = *(const bfrag*)(Vc + r0*64 + ((kcA*2 + hi) ^ r7a)*8);
    v1 = *(const bfrag*)(Vc + r1*64 + ((kcA*2 + hi) ^ r7b)*8);
    v2 = *(const bfrag*)(Vc + r0*64 + ((kcB*2 + hi) ^ r7a)*8);
    v3 = *(const bfrag*)(Vc + r1*64 + ((kcB*2 + hi) ^ r7b)*8);
}

// ---------------------------------------------------------------------------
// Flash attention, 32x32x16 bf16 MFMA, no-max softmax, split-K over grid.z.
// Round-8 form kept verbatim (measured floor ~49 us for this structure:
// six structural levers all ≈null; in-wave dependency chain at ~3.4
// waves/SIMD is the binding constraint).
// ---------------------------------------------------------------------------
__global__ __launch_bounds__(256, 4) void attn_mfma(const short* __restrict__ Qb,
                                                    const short* __restrict__ Kb,
                                                    const short* __restrict__ Vtb,
                                                    float* __restrict__ Opart,
                                                    float* __restrict__ lpart) {
    // 32 KiB total: slot s at lds + s*8192 shorts (K 4096 | V 4096).
    __shared__ short lds[16384];
    const int t = threadIdx.x;
    const int w = t >> 6, lane = t & 63;
    const int l31 = lane & 31, hi = lane >> 5;

    // XCD-chunk swizzle over the (qtile, bh) plane: fid is qtile-fastest.
    const int nwg = gridDim.x * gridDim.y;            // 432
    const int fid = blockIdx.y * gridDim.x + blockIdx.x;
    const int swz = (fid & 7) * (nwg >> 3) + (fid >> 3);
    const int bh  = swz / gridDim.x;
    const int q0  = (swz - bh * gridDim.x) * 128;

    const int split = blockIdx.z;
    const int kbase = split * KSPAN;
    const size_t base = (size_t)bh * N_ * D_;
    const int lrow = lane >> 3;            // row within 8-row segment
    const int lc   = (lane & 7) ^ lrow;    // swizzled source chunk

    short* Qs = lds + 8192;                // overlays slot 1

    // prologue: stage Q tile (128 x 64) into slot1 region, K/V tile 0 into slot0
    #pragma unroll
    for (int r = 0; r < 4; ++r) {
        int s = r*4 + w;
        gl2lds16(Qb + base + (size_t)(q0 + s*8 + lrow)*D_ + lc*8, Qs + s*512);
    }
    #pragma unroll
    for (int r = 0; r < 2; ++r) {
        int s = r*4 + w;
        int row = s*8 + lrow;
        gl2lds16(Kb  + base + (size_t)(kbase+row)*D_ + lc*8,    lds + s*512);
        gl2lds16(Vtb + (size_t)(bh*D_ + row)*N_ + kbase + lc*8, lds + 4096 + s*512);
    }
    __syncthreads();                       // Q + tile0 staged (full drain, once)

    // hoist Q B-frags (loop-invariant)
    bfrag qf[4];
    {
        int row = w*32 + l31, r7 = row & 7;
        #pragma unroll
        for (int kc = 0; kc < 4; ++kc)
            qf[kc] = *(const bfrag*)(Qs + row*64 + ((kc*2 + hi) ^ r7)*8);
    }
    __syncthreads();                       // Q-frag reads done before slot1 reuse

    // ones B-frag for the l (row-sum) MFMA
    bfrag vones;
    #pragma unroll
    for (int j = 0; j < 8; ++j) vones[j] = (short)0x3f80;

    ffrag16 oacc0, oacc1, lfr;
    #pragma unroll
    for (int r = 0; r < 16; ++r) { oacc0[r] = 0.f; oacc1[r] = 0.f; lfr[r] = 0.f; }

    const int NT = KSPAN / 64;             // 18

    // deferred state (kt1 of the previous tile)
    ufrag pP0, pP1;
    bfrag vP0, vP1, vP2, vP3;

    // ---- prime: tile 0 (slot 0); kt0 PV'd in place, kt1 deferred ----
    {
        // issue stage(tile 1) -> slot 1 (overwrites Q region; qf already hoisted)
        const int k0n = kbase + 64;
        #pragma unroll
        for (int r = 0; r < 2; ++r) {
            int s = r*4 + w;
            int row = s*8 + lrow;
            gl2lds16(Kb  + base + (size_t)(k0n+row)*D_ + lc*8,    lds + 8192 + s*512);
            gl2lds16(Vtb + (size_t)(bh*D_ + row)*N_ + k0n + lc*8, lds + 12288 + s*512);
        }
        const short* Kc = lds;
        const short* Vc = lds + 4096;
        ufrag a0, a1;
        qkpack(Kc, qf, 0, l31, hi, a0, a1);
        __builtin_amdgcn_s_setprio(1);
        pv_lds(a0, a1, Vc, 0, l31, hi, vones, oacc0, oacc1, lfr);
        __builtin_amdgcn_s_setprio(0);
        qkpack(Kc, qf, 1, l31, hi, pP0, pP1);
        vload4(Vc, 1, l31, hi, vP0, vP1, vP2, vP3);
        __builtin_amdgcn_s_barrier();      // tile0 reads done before slot0 reuse
    }

    // ---- tiles 1..NT-1 ----
    for (int ti = 1; ti < NT; ++ti) {
        const int cur = ti & 1;
        const short* Kc = lds + cur*8192;
        const short* Vc = Kc + 4096;

        if (ti + 1 < NT) {                 // prefetch next tile into slot cur^1
            short* Kn = lds + (cur^1)*8192;
            const int k0n = kbase + (ti+1)*64;
            #pragma unroll
            for (int r = 0; r < 2; ++r) {
                int s = r*4 + w;
                int row = s*8 + lrow;
                gl2lds16(Kb  + base + (size_t)(k0n+row)*D_ + lc*8,    Kn + s*512);
                gl2lds16(Vtb + (size_t)(bh*D_ + row)*N_ + k0n + lc*8, Kn + 4096 + s*512);
            }
            wait_vm4();
        } else {
            wait_vm0();
        }
        __builtin_amdgcn_s_barrier();      // tile ti visible

        // kt0: QK, then {deferred PV (reg-only, independent) | exp/pack}
        ufrag a0, a1;
        qkpack(Kc, qf, 0, l31, hi, a0, a1);
        __builtin_amdgcn_s_setprio(1);
        pv_reg(pP0, pP1, vP0, vP1, vP2, vP3, vones, oacc0, oacc1, lfr);
        pv_lds(a0, a1, Vc, 0, l31, hi, vones, oacc0, oacc1, lfr);
        __builtin_amdgcn_s_setprio(0);
        // kt1: QK/exp/pack, then save P + V to regs for next iteration
        qkpack(Kc, qf, 1, l31, hi, pP0, pP1);
        vload4(Vc, 1, l31, hi, vP0, vP1, vP2, vP3);
        __builtin_amdgcn_s_barrier();      // tile ti reads done before slot reuse
    }

    // epilogue: drain the last deferred kt
    pv_reg(pP0, pP1, vP0, vP1, vP2, vP3, vones, oacc0, oacc1, lfr);

    const int b = bh / HEADS, head = bh - b*HEADS;
    float* Op = Opart + (size_t)split * M_ * C_;
    float* lp = lpart + (size_t)split * (B_*HEADS) * N_;

    // lfr: every column (lane) holds l[q-row]; rows mapped like oacc
    if (l31 == 0) {
        #pragma unroll
        for (int r = 0; r < 16; ++r) {
            int n = q0 + w*32 + (r & 3) + 8*(r >> 2) + 4*hi;
            lp[bh*N_ + n] = lfr[r];
        }
    }

    #pragma unroll
    for (int r = 0; r < 16; ++r) {
        int n = q0 + w*32 + (r & 3) + 8*(r >> 2) + 4*hi;
        int c = head*D_ + l31;
        Op[((size_t)b*N_ + n)*C_ + c] = oacc0[r];
        Op[((size_t)b*N_ + n)*C_ + c + 32] = oacc1[r];
    }
}

// ---------------------------------------------------------------------------
// Merge split-K partials: Ob = (sum_s O_s) / (sum_s l_s), bf16 out.
// ---------------------------------------------------------------------------
__global__ __launch_bounds__(256) void attn_merge(const float* __restrict__ Opart,
                                                  const float* __restrict__ lpart,
                                                  short* __restrict__ Ob) {
    int i = blockIdx.x * 256 + threadIdx.x;          // over M_*C_/4
    int m = i / (C_/4);
    int c = (i - m*(C_/4)) * 4;
    int b = m / N_, n = m - b*N_;
    int bh = b*HEADS + (c >> 6);
    float4 o0 = ((const float4*)Opart)[i];
    float4 o1 = ((const float4*)(Opart + (size_t)M_*C_))[i];
    float l = lpart[bh*N_ + n] + lpart[(B_*HEADS)*N_ + bh*N_ + n];
    float inv = 1.f / l;
    short4 o;
    o.x = f2bf((o0.x + o1.x) * inv);
    o.y = f2bf((o0.y + o1.y) * inv);
    o.z = f2bf((o0.z + o1.z) * inv);
    o.w = f2bf((o0.w + o1.w) * inv);
    ((short4*)Ob)[i] = o;
}

// ---------------------------------------------------------------------------
// Proj GEMM: out[m][f] = sum_c O[m][c]*w[f][c] + bias[f], fp32 out.
// Same 3-slot 2-deep pipeline + XCD swizzle (216 blocks % 8 == 0).
// ---------------------------------------------------------------------------
__global__ __launch_bounds__(256) void proj_gemm(const short* __restrict__ Ab,
                                                 const short* __restrict__ wb,
                                                 const float* __restrict__ bias,
                                                 float* __restrict__ out) {
    __shared__ short As[3][128*32];
    __shared__ short Bs[3][128*32];
    const int t = threadIdx.x;
    const int w = t >> 6, lane = t & 63;
    const int quad = lane >> 4, l15 = lane & 15;
    const int wr = w >> 1, wc = w & 1;

    const int nwg = gridDim.x * gridDim.y;
    const int bid = blockIdx.y * gridDim.x + blockIdx.x;
    const int swz = (bid & 7) * (nwg >> 3) + (bid >> 3);
    const int m0 = (swz / gridDim.x) * 128, f0 = (swz % gridDim.x) * 128;

    const int srow = lane >> 2;
    const int skk  = (lane & 3) * 8;

    ffrag acc[4][4] = {};

    // prologue: issue K-steps 0,1 into slots 0,1
    #pragma unroll
    for (int r = 0; r < 2; ++r) {
        int seg = r*4 + w;
        int row = seg*16 + srow;
        gl2lds16(Ab + (size_t)(m0+row)*C_ + skk, As[0] + seg*512);
        gl2lds16(wb + (size_t)(f0+row)*C_ + skk, Bs[0] + seg*512);
    }
    #pragma unroll
    for (int r = 0; r < 2; ++r) {
        int seg = r*4 + w;
        int row = seg*16 + srow;
        gl2lds16(Ab + (size_t)(m0+row)*C_ + 32 + skk, As[1] + seg*512);
        gl2lds16(wb + (size_t)(f0+row)*C_ + 32 + skk, Bs[1] + seg*512);
    }

    const int NKT = C_/32;                 // 24
    int cur = 0;
    for (int kt = 0; kt < NKT; ++kt) {
        int pf = cur + 2; if (pf >= 3) pf -= 3;
        if (kt + 2 < NKT) {
            const int k0n = (kt+2)*32;
            #pragma unroll
            for (int r = 0; r < 2; ++r) {
                int seg = r*4 + w;
                int row = seg*16 + srow;
                gl2lds16(Ab + (size_t)(m0+row)*C_ + k0n + skk, As[pf] + seg*512);
                gl2lds16(wb + (size_t)(f0+row)*C_ + k0n + skk, Bs[pf] + seg*512);
            }
            wait_vm8();
        } else if (kt + 1 < NKT) {
            wait_vm4();
        } else {
            wait_vm0();
        }
        __builtin_amdgcn_s_barrier();

        bfrag af[4], bf[4];
        #pragma unroll
        for (int i = 0; i < 4; ++i)
            af[i] = *(const bfrag*)(As[cur] + (wr*64 + i*16 + l15)*32 + quad*8);
        #pragma unroll
        for (int j = 0; j < 4; ++j)
            bf[j] = *(const bfrag*)(Bs[cur] + (wc*64 + j*16 + l15)*32 + quad*8);
        #pragma unroll
        for (int i = 0; i < 4; ++i)
            #pragma unroll
            for (int j = 0; j < 4; ++j)
                acc[i][j] = __builtin_amdgcn_mfma_f32_16x16x32_bf16(af[i], bf[j], acc[i][j], 0, 0, 0);
        __builtin_amdgcn_s_barrier();
        cur = cur + 1; if (cur >= 3) cur = 0;
    }

    #pragma unroll
    for (int i = 0; i < 4; ++i) {
        int mbase = m0 + wr*64 + i*16 + quad*4;
        #pragma unroll
        for (int j = 0; j < 4; ++j) {
            int f = f0 + wc*64 + j*16 + l15;
            float bv = bias[f];
            #pragma unroll
            for (int r = 0; r < 4; ++r)
                out[(size_t)(mbase + r)*C_ + f] = acc[i][j][r] + bv;
        }
    }
}

// ---------------------------------------------------------------------------
extern "C" void kernel_launch(void* const* d_in, const int* in_sizes, int n_in,
                              void* d_out, int out_size, void* d_ws, size_t ws_size,
                              hipStream_t stream) {
    const float* x      = (const float*)d_in[0];
    const float* qkv_w  = (const float*)d_in[3];
    const float* proj_w = (const float*)d_in[4];
    const float* proj_b = (const float*)d_in[5];
    float* out = (float*)d_out;

    const size_t nx = (size_t)M_ * C_;        // 3,538,944
    const size_t nq = (size_t)F3 * C_;        // 1,769,472
    const size_t np = (size_t)C_ * C_;        //   589,824
    short* xb  = (short*)d_ws;
    short* qwb = xb  + nx;
    short* pwb = qwb + nq;
    short* Qb  = pwb + np;
    short* Kb  = Qb  + nx;
    short* Vtb = Kb  + nx;
    short* Ob  = Vtb + nx;
    float* Opart = (float*)(Ob + nx);                       // SPLITS * M_*C_
    float* lpart = Opart + (size_t)SPLITS * M_ * C_;        // SPLITS * 24*N_

    const int ncast4 = (int)((nx + nq + np) / 4);
    cast_all<<<dim3((ncast4 + 255)/256), 256, 0, stream>>>(x, qkv_w, proj_w, xb);

    qkv_gemm<<<dim3(F3/128, M_/128), 256, 0, stream>>>(xb, qwb, Qb, Kb, Vtb);
    attn_mfma<<<dim3(N_/128, B_*HEADS, SPLITS), 256, 0, stream>>>(Qb, Kb, Vtb, Opart, lpart);
    attn_merge<<<dim3(((int)(nx/4) + 255)/256), 256, 0, stream>>>(Opart, lpart, Ob);
    proj_gemm<<<dim3(C_/128, M_/128), 256, 0, stream>>>(Ob, pwb, proj_b, out);
}